// Round 9
// baseline (197.311 us; speedup 1.0000x reference)
//
#include <hip/hip_runtime.h>

#define Bsz 1024
#define Nn 256
#define Fdim 8
#define Eedge 1024
#define OUTC 128
#define CADV 192
#define CTOT 256
#define Ktot 32768   // Nn * OUTC
#define ASTR 40      // LDS row stride in bf16 (32+8): 16B-aligned, 2-way banks (free)
#define XSTR 24      // x_s/rw_s row stride (48 B = 12-bank stride -> 2-way, free)
#define NSK 64       // split-K chunks (proven ws >= 81 MB; part = 64 MB)

typedef __attribute__((ext_vector_type(8))) short short8;
typedef __attribute__((ext_vector_type(4))) float float4v;

static __device__ inline unsigned short f2bf(float f) {
  union { float f; unsigned u; } v; v.f = f;
  unsigned r = v.u + 0x7FFFu + ((v.u >> 16) & 1u);  // round-nearest-even
  return (unsigned short)(r >> 16);
}
static __device__ inline float bf2f(unsigned short h) {
  union { unsigned u; float f; } v; v.u = ((unsigned)h) << 16;
  return v.f;
}
static __device__ inline uint4 pack8(const unsigned short* b) {
  uint4 v;
  v.x = (unsigned)b[0] | ((unsigned)b[1] << 16);
  v.y = (unsigned)b[2] | ((unsigned)b[3] << 16);
  v.z = (unsigned)b[4] | ((unsigned)b[5] << 16);
  v.w = (unsigned)b[6] | ((unsigned)b[7] << 16);
  return v;
}

// ---------------------------------------------------------------------------
// K2 (R18): ONE fused GEMM dispatch — prep kernel deleted.
//  * B-staging reads advw/v1w fp32 DIRECTLY with the transpose pattern and
//    converts to bf16 at the LDS-write site (wt buffer never exists; advw
//    chunk is L2-resident per XCD, 8 mb-blocks share it).
//  * mb==0 blocks compute the b=0 tail (h, full theta, S scatter, 4 feat0
//    rows for their chunk) in a PROLOGUE, scratch aliased into b_s[0];
//    A-gen patch reads feat0 from LDS. No cross-block ordering anywhere.
//  * Geometry = R13-proven: NS=64 x mb=8, grid 512, 2 blocks/CU,
//    LDS 81.4 KB <= 81.9 KB budget.
// ---------------------------------------------------------------------------
__global__ __launch_bounds__(512, 2) void gemm_mfma(
    const float* __restrict__ x, const float* __restrict__ advw,
    const float* __restrict__ v1w, const float* __restrict__ rootw,
    const float* __restrict__ convb, const float* __restrict__ w1,
    const float* __restrict__ b1, const float* __restrict__ w2,
    const float* __restrict__ b2, const int* __restrict__ ei,
    float* __restrict__ part, int iters, int ns)
{
  __shared__ short a_s[2][128 * ASTR];   // 20480 B
  __shared__ short b_s[2][256 * ASTR];   // 40960 B (buffer 0 doubles as
                                         //   fp32 scratch in mb==0 prologue)
  __shared__ short x_s[2][128 * XSTR];   // 12288 B
  __shared__ short rw_s[128 * XSTR];     // 6144 B
  __shared__ float convb_s[128];         // 512 B
  __shared__ unsigned short f0_s[4][128];// 1024 B  feat0 rows (mb==0 chunk)
  int t = threadIdx.x;
  int ch = blockIdx.x;   // K chunk (XCD = ch%8; 8 mb-blocks share its L2 set)
  int mb = blockIdx.y;   // 0..7
  int wave = t >> 6, lane = t & 63;
  int wm = wave >> 2, wn = wave & 3;   // 2 x 4 wave grid over 128x256 tile
  int lm = lane & 15, lq = lane >> 4;

  float4v acc[4][4];
#pragma unroll
  for (int i = 0; i < 4; ++i)
#pragma unroll
    for (int j = 0; j < 4; ++j) acc[i][j] = (float4v)0.f;

  int kt0 = ch * iters;
  int iters4 = iters >> 2;          // nodes in this chunk (4)
  int n0 = ch * iters4;             // first node
  int wr0 = (t >> 2) * ASTR + (t & 3) * 8;
  int u1 = t + 512;
  int wr1 = (u1 >> 2) * ASTR + (u1 & 3) * 8;

  // B-source decode for the two staged rows this thread owns:
  //   u -> col c2 = u>>2 (0..255), k-slice ks = u&3 (8 k each)
  //   col<192 -> advw[k*192+col]; col>=192 -> v1w[k*64+col-192]
  int c2a = t >> 2,        ksa = t & 3;
  int c2b = u1 >> 2,       ksb = u1 & 3;
  const float* bsrcA = (c2a < CADV) ? (advw + c2a) : (v1w + (c2a - CADV));
  int bstrA = (c2a < CADV) ? CADV : 64;
  const float* bsrcB = (c2b < CADV) ? (advw + c2b) : (v1w + (c2b - CADV));
  int bstrB = (c2b < CADV) ? CADV : 64;

  // ---- common prologue staging ----
  if (t < 128) {
    float wv[8];
#pragma unroll
    for (int f = 0; f < 8; ++f) wv[f] = rootw[f * OUTC + t];
    unsigned short wh[8], wl[8];
#pragma unroll
    for (int f = 0; f < 8; ++f) {
      wh[f] = f2bf(wv[f]);
      wl[f] = f2bf(wv[f] - bf2f(wh[f]));
    }
    *(uint4*)(rw_s + t * XSTR)     = pack8(wh);
    *(uint4*)(rw_s + t * XSTR + 8) = pack8(wl);
    convb_s[t] = convb[t];
  }
  int xr = (t & 255) >> 1, xh = t & 1;
  const float* xgb = x + ((size_t)(mb * 128 + xr) * Nn) * Fdim + xh * 4;
  if (t < 256) {
    float4 xv = *(const float4*)(xgb + (size_t)n0 * Fdim);
    float xa[4] = {xv.x, xv.y, xv.z, xv.w};
    unsigned short hh[4], ll[4];
#pragma unroll
    for (int f = 0; f < 4; ++f) {
      hh[f] = f2bf(xa[f]);
      ll[f] = f2bf(xa[f] - bf2f(hh[f]));
    }
    uint2 dh, dl;
    dh.x = (unsigned)hh[0] | ((unsigned)hh[1] << 16);
    dh.y = (unsigned)hh[2] | ((unsigned)hh[3] << 16);
    dl.x = (unsigned)ll[0] | ((unsigned)ll[1] << 16);
    dl.y = (unsigned)ll[2] | ((unsigned)ll[3] << 16);
    *(uint2*)(x_s[0] + xr * XSTR + xh * 4)     = dh;
    *(uint2*)(x_s[0] + xr * XSTR + 8 + xh * 4) = dl;
  }

  // ---- mb==0 prologue: b=0 tail for this chunk (scratch in b_s[0]) ----
  if (mb == 0) {
    float* fs   = (float*)b_s;     // 12.6 KB of the 20 KB buffer 0
    float* h_s  = fs;              // 64
    float* th_s = fs + 64;         // 1024  [f*128 + o]
    float* S_s  = fs + 1088;       // 2048
    int*   flag = (int*)(fs + 3136);
    if (t < 64) h_s[t] = fmaxf(w1[t] + b1[t], 0.f);
    for (int i = t; i < Nn * Fdim; i += 512) S_s[i] = 0.f;
    if (t == 0) {
      int z = 0;
      for (int i = 1; i < 16; i += 2) z |= ei[i];
      *flag = (z == 0);  // little-endian int64 detection
    }
    __syncthreads();
    int is64 = *flag;
    // theta: 2 cols per thread, 64-deep (w2 reads coalesced across threads)
#pragma unroll
    for (int cc = 0; cc < 2; ++cc) {
      int c = t + cc * 512;
      float a2 = b2[c];
#pragma unroll
      for (int j = 0; j < 64; ++j) a2 += h_s[j] * w2[(size_t)j * 1024 + c];
      th_s[c] = a2;
    }
    // edge scatter: 2 edges per thread
    int s0, t0, s1, t1;
    if (is64) { s0 = ei[2 * t];         t0 = ei[2 * (Eedge + t)];
                s1 = ei[2 * (t + 512)]; t1 = ei[2 * (Eedge + t + 512)]; }
    else      { s0 = ei[t];             t0 = ei[Eedge + t];
                s1 = ei[t + 512];       t1 = ei[Eedge + t + 512]; }
    s0 &= 255; t0 &= 255; s1 &= 255; t1 &= 255;
    {
      const float* xp0 = x + s0 * Fdim;
      const float* xp1 = x + s1 * Fdim;
#pragma unroll
      for (int f = 0; f < Fdim; ++f) {
        atomicAdd(&S_s[t0 * Fdim + f], xp0[f]);
        atomicAdd(&S_s[t1 * Fdim + f], xp1[f]);
      }
    }
    __syncthreads();
    // feat0 rows for nodes n0..n0+3: thread -> (node, o)
    {
      int nd = t >> 7, o = t & 127, node = n0 + nd;
      const float* xp = x + node * Fdim;   // batch-0 rows, L2-hot
      float z = convb[o];
#pragma unroll
      for (int f = 0; f < 8; ++f)
        z += xp[f] * rootw[f * OUTC + o] + S_s[node * Fdim + f] * th_s[f * 128 + o];
      f0_s[nd][o] = f2bf(fmaxf(z, 0.f));
    }
    __syncthreads();   // scratch consumed; b_s[0] is free for the K-loop
  }
  __syncthreads();

  // stage A-subtile for iter 0 (g=0, node n0, x_s[0] -> a_s[0])
  {
    int bloc = wave * 16 + lm;
    short8 xf = (short8)0;
    if (lq == 0 || lq == 2) xf = *(const short8*)(x_s[0] + bloc * XSTR);
    else if (lq == 1)       xf = *(const short8*)(x_s[0] + bloc * XSTR + 8);
#pragma unroll
    for (int tt = 0; tt < 2; ++tt) {
      int ot = tt;                       // g=0
      short8 wf = (short8)0;
      if (lq <= 1)      wf = *(const short8*)(rw_s + (ot * 16 + lm) * XSTR);
      else if (lq == 2) wf = *(const short8*)(rw_s + (ot * 16 + lm) * XSTR + 8);
      float4v c = __builtin_amdgcn_mfma_f32_16x16x32_bf16(wf, xf, (float4v)0.f, 0, 0, 0);
      int o0 = ot * 16 + lq * 4;
      float4 cb = *(const float4*)(convb_s + o0);
      unsigned d0 = (unsigned)f2bf(fmaxf(c[0] + cb.x, 0.f)) |
                    ((unsigned)f2bf(fmaxf(c[1] + cb.y, 0.f)) << 16);
      unsigned d1 = (unsigned)f2bf(fmaxf(c[2] + cb.z, 0.f)) |
                    ((unsigned)f2bf(fmaxf(c[3] + cb.w, 0.f)) << 16);
      if (mb == 0 && bloc == 0) {
        const unsigned* f0p = (const unsigned*)(&f0_s[0][o0]);
        d0 = f0p[0]; d1 = f0p[1];
      }
      uint2 dd; dd.x = d0; dd.y = d1;
      *(uint2*)(a_s[0] + bloc * ASTR + tt * 16 + lq * 4) = dd;
    }
  }

  // preload B slab 0 (fp32, transpose pattern)
  float rA[8], rB[8];
  {
    const float* pa = bsrcA + (size_t)(kt0 * 32 + ksa * 8) * bstrA;
    const float* pb2 = bsrcB + (size_t)(kt0 * 32 + ksb * 8) * bstrB;
#pragma unroll
    for (int i = 0; i < 8; ++i) { rA[i] = pa[i * bstrA]; rB[i] = pb2[i * bstrB]; }
  }
  float4 xpf = {0.f, 0.f, 0.f, 0.f};

  for (int kk = 0; kk < iters; ++kk) {
    int g = kk & 3, grp = kk >> 2;
    short* bb = b_s[kk & 1];
    {
      unsigned short ca[8], cbv[8];
#pragma unroll
      for (int i = 0; i < 8; ++i) { ca[i] = f2bf(rA[i]); cbv[i] = f2bf(rB[i]); }
      *(uint4*)(bb + wr0) = pack8(ca);
      *(uint4*)(bb + wr1) = pack8(cbv);
    }
    if (g == 0 && grp + 1 < iters4 && t < 256)
      xpf = *(const float4*)(xgb + (size_t)(n0 + grp + 1) * Fdim);
    if (g == 3 && grp + 1 < iters4 && t < 256) {
      float xa[4] = {xpf.x, xpf.y, xpf.z, xpf.w};
      unsigned short hh[4], ll[4];
#pragma unroll
      for (int f = 0; f < 4; ++f) {
        hh[f] = f2bf(xa[f]);
        ll[f] = f2bf(xa[f] - bf2f(hh[f]));
      }
      uint2 dh, dl;
      dh.x = (unsigned)hh[0] | ((unsigned)hh[1] << 16);
      dh.y = (unsigned)hh[2] | ((unsigned)hh[3] << 16);
      dl.x = (unsigned)ll[0] | ((unsigned)ll[1] << 16);
      dl.y = (unsigned)ll[2] | ((unsigned)ll[3] << 16);
      short* xd = x_s[(grp + 1) & 1];
      *(uint2*)(xd + xr * XSTR + xh * 4)     = dh;
      *(uint2*)(xd + xr * XSTR + 8 + xh * 4) = dl;
    }
    if (kk + 1 < iters) {   // issue next-slab fp32 loads pre-barrier (R13)
      const float* pa = bsrcA + (size_t)((kt0 + kk + 1) * 32 + ksa * 8) * bstrA;
      const float* pb2 = bsrcB + (size_t)((kt0 + kk + 1) * 32 + ksb * 8) * bstrB;
#pragma unroll
      for (int i = 0; i < 8; ++i) { rA[i] = pa[i * bstrA]; rB[i] = pb2[i * bstrB]; }
    }
    __syncthreads();

    // main MFMA on tile kk
    short* ab = a_s[kk & 1];
    short8 aF[4];
#pragma unroll
    for (int i = 0; i < 4; ++i)
      aF[i] = *(const short8*)(ab + (wm * 64 + i * 16 + lm) * ASTR + lq * 8);
#pragma unroll
    for (int j = 0; j < 4; ++j) {
      short8 bF = *(const short8*)(bb + (wn * 64 + j * 16 + lm) * ASTR + lq * 8);
#pragma unroll
      for (int i = 0; i < 4; ++i)
        acc[i][j] = __builtin_amdgcn_mfma_f32_16x16x32_bf16(bF, aF[i], acc[i][j], 0, 0, 0);
    }

    // stage A-subtile for iter kk+1 into the other buffer
    if (kk + 1 < iters) {
      int kn = kk + 1;
      int g2 = kn & 3, grp2 = kn >> 2;
      const short* xs = x_s[grp2 & 1];
      short* ad = a_s[kn & 1];
      int bloc = wave * 16 + lm;
      short8 xf = (short8)0;
      if (lq == 0 || lq == 2) xf = *(const short8*)(xs + bloc * XSTR);
      else if (lq == 1)       xf = *(const short8*)(xs + bloc * XSTR + 8);
#pragma unroll
      for (int tt = 0; tt < 2; ++tt) {
        int ot = g2 * 2 + tt;
        short8 wf = (short8)0;
        if (lq <= 1)      wf = *(const short8*)(rw_s + (ot * 16 + lm) * XSTR);
        else if (lq == 2) wf = *(const short8*)(rw_s + (ot * 16 + lm) * XSTR + 8);
        float4v c = __builtin_amdgcn_mfma_f32_16x16x32_bf16(wf, xf, (float4v)0.f, 0, 0, 0);
        int o0 = ot * 16 + lq * 4;
        float4 cb = *(const float4*)(convb_s + o0);
        unsigned d0 = (unsigned)f2bf(fmaxf(c[0] + cb.x, 0.f)) |
                      ((unsigned)f2bf(fmaxf(c[1] + cb.y, 0.f)) << 16);
        unsigned d1 = (unsigned)f2bf(fmaxf(c[2] + cb.z, 0.f)) |
                      ((unsigned)f2bf(fmaxf(c[3] + cb.w, 0.f)) << 16);
        if (mb == 0 && bloc == 0) {
          const unsigned* f0p = (const unsigned*)(&f0_s[grp2][o0]);
          d0 = f0p[0]; d1 = f0p[1];
        }
        uint2 dd; dd.x = d0; dd.y = d1;
        *(uint2*)(ad + bloc * ASTR + tt * 16 + lq * 4) = dd;
      }
    }
  }

  // epilogue: part layout [b][ch][c]; per-lane dwordx4
  float* pb = part + ((size_t)(mb * 128) * ns + ch) * CTOT;
#pragma unroll
  for (int i = 0; i < 4; ++i) {
    int m = wm * 64 + i * 16 + lm;
#pragma unroll
    for (int j = 0; j < 4; ++j) {
      int c = wn * 64 + j * 16 + lq * 4;
      *(float4v*)(pb + (size_t)m * ns * CTOT + c) = acc[i][j];
    }
  }
}

// ---------------------------------------------------------------------------
// K3: reduce fp32 split-K partials (contiguous per block), biases+relu,
// val MLP, dueling combine.
// ---------------------------------------------------------------------------
__global__ __launch_bounds__(256) void final_kernel(
    const float* __restrict__ part, int ns,
    const float* __restrict__ advb, const float* __restrict__ v1b,
    const float* __restrict__ v2w, const float* __restrict__ v2b,
    const float* __restrict__ v3w, const float* __restrict__ v3b,
    float* __restrict__ out)
{
  __shared__ float adv_s[CADV];
  __shared__ float v1_s[64];
  __shared__ float val2_s[64];
  __shared__ float val3_s[64];
  int b = blockIdx.x, t = threadIdx.x;
  float s = 0.f;
  const float* p = part + (size_t)b * ns * CTOT + t;
  for (int i = 0; i < ns; ++i) s += p[(size_t)i * CTOT];
  if (t < CADV) adv_s[t] = fmaxf(s + advb[t], 0.f);
  else          v1_s[t - CADV] = fmaxf(s + v1b[t - CADV], 0.f);
  __syncthreads();
  if (t < 64) {
    float a = v2b[t];
#pragma unroll
    for (int i = 0; i < 64; ++i) a += v1_s[i] * v2w[i * 64 + t];
    val2_s[t] = fmaxf(a, 0.f);
  }
  __syncthreads();
  if (t < 64) {
    float a = v3b[t];
#pragma unroll
    for (int j = 0; j < 64; ++j) a += val2_s[j] * v3w[j * 64 + t];
    val3_s[t] = a;
  }
  __syncthreads();
  if (t < CADV) {
    int d = t / 3;
    float mean = (adv_s[d * 3] + adv_s[d * 3 + 1] + adv_s[d * 3 + 2]) * (1.f / 3.f);
    out[(size_t)b * CADV + t] = val3_s[d] + adv_s[t] - mean;
  }
}

extern "C" void kernel_launch(void* const* d_in, const int* in_sizes, int n_in,
                              void* d_out, int out_size, void* d_ws, size_t ws_size,
                              hipStream_t stream)
{
  (void)in_sizes; (void)n_in; (void)out_size; (void)ws_size;
  const float* x     = (const float*)d_in[0];
  const int*   ei    = (const int*)d_in[1];
  const float* w1    = (const float*)d_in[2];
  const float* b1    = (const float*)d_in[3];
  const float* w2    = (const float*)d_in[4];
  const float* b2    = (const float*)d_in[5];
  const float* rootw = (const float*)d_in[6];
  const float* convb = (const float*)d_in[7];
  const float* advw  = (const float*)d_in[8];
  const float* advb  = (const float*)d_in[9];
  const float* v1w   = (const float*)d_in[10];
  const float* v1b   = (const float*)d_in[11];
  const float* v2w   = (const float*)d_in[12];
  const float* v2b   = (const float*)d_in[13];
  const float* v3w   = (const float*)d_in[14];
  const float* v3b   = (const float*)d_in[15];
  float* out = (float*)d_out;

  // workspace = split-K partials only (64 MB; proven ws >= 81 MB in R3..R17)
  float* part = (float*)d_ws;

  gemm_mfma<<<dim3(NSK, 8), 512, 0, stream>>>(x, advw, v1w, rootw, convb,
                                              w1, b1, w2, b2, ei, part,
                                              1024 / NSK, NSK);
  final_kernel<<<Bsz, 256, 0, stream>>>(part, NSK, advb, v1b, v2w, v2b, v3w,
                                        v3b, out);
}

// Round 10
// 166.834 us; speedup vs baseline: 1.1827x; 1.1827x over previous
//
#include <hip/hip_runtime.h>

#define Bsz 1024
#define Nn 256
#define Fdim 8
#define Eedge 1024
#define OUTC 128
#define CADV 192
#define CTOT 256
#define Ktot 32768   // Nn * OUTC
#define ASTR 40      // LDS row stride in bf16 (32+8): 16B-aligned, 2-way banks (free)
#define XSTR 24      // x_s/rw_s row stride (48 B = 12-bank stride -> 2-way, free)

typedef __attribute__((ext_vector_type(8))) short short8;
typedef __attribute__((ext_vector_type(4))) float float4v;

static __device__ inline unsigned short f2bf(float f) {
  union { float f; unsigned u; } v; v.f = f;
  unsigned r = v.u + 0x7FFFu + ((v.u >> 16) & 1u);  // round-nearest-even
  return (unsigned short)(r >> 16);
}
static __device__ inline float bf2f(unsigned short h) {
  union { unsigned u; float f; } v; v.u = ((unsigned)h) << 16;
  return v.f;
}
static __device__ inline uint4 pack8(const unsigned short* b) {
  uint4 v;
  v.x = (unsigned)b[0] | ((unsigned)b[1] << 16);
  v.y = (unsigned)b[2] | ((unsigned)b[3] << 16);
  v.z = (unsigned)b[4] | ((unsigned)b[5] << 16);
  v.w = (unsigned)b[6] | ((unsigned)b[7] << 16);
  return v;
}

// ---------------------------------------------------------------------------
// K1 (R13-proven): tail x16 (theta + S scatter + feat0 b=0 correction)
// + wt transpose (linear layout; K2 LDS-stages it).
// ---------------------------------------------------------------------------
__global__ __launch_bounds__(256) void prep_feat_kernel(
    const float* __restrict__ x, const int* __restrict__ ei,
    const float* __restrict__ w1, const float* __restrict__ b1,
    const float* __restrict__ w2, const float* __restrict__ b2,
    const float* __restrict__ rootw, const float* __restrict__ convb,
    const float* __restrict__ advw, const float* __restrict__ v1w,
    unsigned short* __restrict__ wt, unsigned short* __restrict__ feat0)
{
  __shared__ __align__(16) char smem[20480];
  int bid = blockIdx.x, t = threadIdx.x;

  if (bid < 16) {
    // ---- tail x16: theta slice + redundant scatter S + feat0 o-slice ----
    float* fs   = (float*)smem;
    float* h_s  = fs;            // 64
    float* rw_s = fs + 64;       // 64
    float* th_s = fs + 128;      // 64
    float* pt_s = fs + 192;      // 256
    float* S_s  = fs + 448;      // 2048
    int*   flag = (int*)(fs + 2496);
    int obase = bid * 8;

    if (t < 64) {
      h_s[t]  = fmaxf(w1[t] + b1[t], 0.f);
      rw_s[t] = rootw[(t >> 3) * OUTC + obase + (t & 7)];
    }
    for (int i = t; i < Nn * Fdim; i += 256) S_s[i] = 0.f;
    if (t == 0) {
      int z = 0;
      for (int i = 1; i < 16; i += 2) z |= ei[i];
      *flag = (z == 0);  // little-endian int64 detection
    }
    __syncthreads();
    int is64 = *flag;

    {  // theta slice: 64 cols x 64-deep reduction across 4 waves
      int l = t & 63, g = t >> 6;
      int c = (l >> 3) * 128 + obase + (l & 7);
      float p = 0.f;
#pragma unroll
      for (int j = 0; j < 16; ++j)
        p += h_s[g * 16 + j] * w2[(size_t)(g * 16 + j) * 1024 + c];
      pt_s[t] = p;
    }
    int srcs[4], tgts[4];
#pragma unroll
    for (int q = 0; q < 4; ++q) {
      int e = t + q * 256;
      if (is64) { srcs[q] = ei[2 * e]; tgts[q] = ei[2 * (Eedge + e)]; }
      else      { srcs[q] = ei[e];     tgts[q] = ei[Eedge + e]; }
      srcs[q] &= 255; tgts[q] &= 255;
    }
    __syncthreads();
    if (t < 64) {
      int c = (t >> 3) * 128 + obase + (t & 7);
      th_s[t] = b2[c] + pt_s[t] + pt_s[t + 64] + pt_s[t + 128] + pt_s[t + 192];
    }
#pragma unroll
    for (int q = 0; q < 4; ++q) {
      const float* xp = x + srcs[q] * Fdim;
#pragma unroll
      for (int f = 0; f < Fdim; ++f)
        atomicAdd(&S_s[tgts[q] * Fdim + f], xp[f]);
    }
    __syncthreads();
    {  // feat0 slice: thread t = node n, 8 o-columns
      int n = t;
      const float* xp = x + n * Fdim;
      float4 xa = *(const float4*)xp;
      float4 xb = *(const float4*)(xp + 4);
      float xv[8] = {xa.x, xa.y, xa.z, xa.w, xb.x, xb.y, xb.z, xb.w};
      float sv[8];
#pragma unroll
      for (int f = 0; f < 8; ++f) sv[f] = S_s[n * Fdim + f];
      unsigned short buf[8];
#pragma unroll
      for (int oi = 0; oi < 8; ++oi) {
        float z = convb[obase + oi];
#pragma unroll
        for (int f = 0; f < 8; ++f)
          z += xv[f] * rw_s[f * 8 + oi] + sv[f] * th_s[f * 8 + oi];
        buf[oi] = f2bf(fmaxf(z, 0.f));
      }
      *(uint4*)(feat0 + (size_t)n * OUTC + obase) = pack8(buf);
    }
  } else {
    // ---- wt transpose: 32-deep load batch, LDS-staged, coalesced flush ----
    unsigned short* st = (unsigned short*)smem;  // 20 KB
    int kt = bid - 16, c = t;
    const float* src; int stride, col;
    if (c < CADV) { src = advw; stride = CADV; col = c; }
    else          { src = v1w;  stride = 64;   col = c - CADV; }
    float v[32];
#pragma unroll
    for (int i = 0; i < 32; ++i)
      v[i] = src[(size_t)(kt * 32 + i) * stride + col];
    unsigned short bv[32];
#pragma unroll
    for (int i = 0; i < 32; ++i) bv[i] = f2bf(v[i]);
#pragma unroll
    for (int p = 0; p < 4; ++p)
      *(uint4*)(st + c * ASTR + p * 8) = pack8(bv + p * 8);
    __syncthreads();
    uint4* dst = (uint4*)(wt + (size_t)kt * (CTOT * 32));
    for (int r = 0; r < 4; ++r) {
      int s = r * 256 + c;        // lane-consecutive -> coalesced
      dst[s] = *(const uint4*)(st + (s >> 2) * ASTR + (s & 3) * 8);
    }
  }
}

// ---------------------------------------------------------------------------
// K2 (R13-proven, 43.3 us): fused-A MFMA GEMM.
// Grid dim3(NS, 8): XCD = ch%8, all 8 mb-blocks sharing a wt chunk co-reside
// on one XCD (FETCH 14.7 MB). part layout [b][ch][c]. LDS-staged B dbuf,
// pre-barrier prefetch, single barrier/iter. R14-R18 excursions (post-barrier
// issue, B-direct, 4-blk small tiles, mb=32, full fusion) all <= this config.
// ---------------------------------------------------------------------------
__global__ __launch_bounds__(512, 2) void gemm_mfma(
    const float* __restrict__ x, const unsigned short* __restrict__ wt,
    const float* __restrict__ rootw, const float* __restrict__ convb,
    const unsigned short* __restrict__ feat0, float* __restrict__ part,
    int iters, int ns)
{
  __shared__ short a_s[2][128 * ASTR];   // 20 KB
  __shared__ short b_s[2][256 * ASTR];   // 40 KB
  __shared__ short x_s[2][128 * XSTR];   // 12 KB [b][xh0..7 | xl0..7 | pad]
  __shared__ short rw_s[128 * XSTR];     // 6 KB  [o][wh0..7 | wl0..7 | pad]
  __shared__ float convb_s[128];         // 0.5 KB
  int t = threadIdx.x;
  int ch = blockIdx.x;   // K chunk
  int mb = blockIdx.y;   // 0..7
  int wave = t >> 6, lane = t & 63;
  int wm = wave >> 2, wn = wave & 3;   // 2 x 4 wave grid
  int lm = lane & 15, lq = lane >> 4;

  float4v acc[4][4];
#pragma unroll
  for (int i = 0; i < 4; ++i)
#pragma unroll
    for (int j = 0; j < 4; ++j) acc[i][j] = (float4v)0.f;

  int kt0 = ch * iters;
  int iters4 = iters >> 2;          // nodes in this chunk
  int n0 = ch * iters4;             // first node
  int wr0 = (t >> 2) * ASTR + (t & 3) * 8;
  int u1 = t + 512;
  int wr1 = (u1 >> 2) * ASTR + (u1 & 3) * 8;

  // ---- prologue staging ----
  if (t < 128) {
    float wv[8];
#pragma unroll
    for (int f = 0; f < 8; ++f) wv[f] = rootw[f * OUTC + t];
    unsigned short wh[8], wl[8];
#pragma unroll
    for (int f = 0; f < 8; ++f) {
      wh[f] = f2bf(wv[f]);
      wl[f] = f2bf(wv[f] - bf2f(wh[f]));
    }
    *(uint4*)(rw_s + t * XSTR)     = pack8(wh);
    *(uint4*)(rw_s + t * XSTR + 8) = pack8(wl);
    convb_s[t] = convb[t];
  }
  int xr = (t & 255) >> 1, xh = t & 1;
  const float* xgb = x + ((size_t)(mb * 128 + xr) * Nn) * Fdim + xh * 4;
  if (t < 256) {
    float4 xv = *(const float4*)(xgb + (size_t)n0 * Fdim);
    float xa[4] = {xv.x, xv.y, xv.z, xv.w};
    unsigned short hh[4], ll[4];
#pragma unroll
    for (int f = 0; f < 4; ++f) {
      hh[f] = f2bf(xa[f]);
      ll[f] = f2bf(xa[f] - bf2f(hh[f]));
    }
    uint2 dh, dl;
    dh.x = (unsigned)hh[0] | ((unsigned)hh[1] << 16);
    dh.y = (unsigned)hh[2] | ((unsigned)hh[3] << 16);
    dl.x = (unsigned)ll[0] | ((unsigned)ll[1] << 16);
    dl.y = (unsigned)ll[2] | ((unsigned)ll[3] << 16);
    *(uint2*)(x_s[0] + xr * XSTR + xh * 4)     = dh;
    *(uint2*)(x_s[0] + xr * XSTR + 8 + xh * 4) = dl;
  }
  __syncthreads();

  // stage A-subtile for iter 0 (g=0, node n0, x_s[0] -> a_s[0])
  {
    int bloc = wave * 16 + lm;
    short8 xf = (short8)0;
    if (lq == 0 || lq == 2) xf = *(const short8*)(x_s[0] + bloc * XSTR);
    else if (lq == 1)       xf = *(const short8*)(x_s[0] + bloc * XSTR + 8);
#pragma unroll
    for (int tt = 0; tt < 2; ++tt) {
      int ot = tt;                       // g=0
      short8 wf = (short8)0;
      if (lq <= 1)      wf = *(const short8*)(rw_s + (ot * 16 + lm) * XSTR);
      else if (lq == 2) wf = *(const short8*)(rw_s + (ot * 16 + lm) * XSTR + 8);
      float4v c = __builtin_amdgcn_mfma_f32_16x16x32_bf16(wf, xf, (float4v)0.f, 0, 0, 0);
      int o0 = ot * 16 + lq * 4;
      float4 cb = *(const float4*)(convb_s + o0);
      unsigned d0 = (unsigned)f2bf(fmaxf(c[0] + cb.x, 0.f)) |
                    ((unsigned)f2bf(fmaxf(c[1] + cb.y, 0.f)) << 16);
      unsigned d1 = (unsigned)f2bf(fmaxf(c[2] + cb.z, 0.f)) |
                    ((unsigned)f2bf(fmaxf(c[3] + cb.w, 0.f)) << 16);
      if (mb == 0 && bloc == 0) {
        const unsigned* f0p = (const unsigned*)(feat0 + ((size_t)n0 * OUTC + o0));
        d0 = f0p[0]; d1 = f0p[1];
      }
      uint2 dd; dd.x = d0; dd.y = d1;
      *(uint2*)(a_s[0] + bloc * ASTR + tt * 16 + lq * 4) = dd;
    }
  }

  // preload B tile 0
  const uint4* gB = (const uint4*)wt + (size_t)kt0 * 1024;
  uint4 vb0 = gB[t], vb1 = gB[t + 512];
  float4 xpf = {0.f, 0.f, 0.f, 0.f};

  for (int kk = 0; kk < iters; ++kk) {
    int g = kk & 3, grp = kk >> 2;
    short* bb = b_s[kk & 1];
    *(uint4*)(bb + wr0) = vb0;
    *(uint4*)(bb + wr1) = vb1;
    if (g == 0 && grp + 1 < iters4 && t < 256)
      xpf = *(const float4*)(xgb + (size_t)(n0 + grp + 1) * Fdim);
    if (g == 3 && grp + 1 < iters4 && t < 256) {
      float xa[4] = {xpf.x, xpf.y, xpf.z, xpf.w};
      unsigned short hh[4], ll[4];
#pragma unroll
      for (int f = 0; f < 4; ++f) {
        hh[f] = f2bf(xa[f]);
        ll[f] = f2bf(xa[f] - bf2f(hh[f]));
      }
      uint2 dh, dl;
      dh.x = (unsigned)hh[0] | ((unsigned)hh[1] << 16);
      dh.y = (unsigned)hh[2] | ((unsigned)hh[3] << 16);
      dl.x = (unsigned)ll[0] | ((unsigned)ll[1] << 16);
      dl.y = (unsigned)ll[2] | ((unsigned)ll[3] << 16);
      short* xd = x_s[(grp + 1) & 1];
      *(uint2*)(xd + xr * XSTR + xh * 4)     = dh;
      *(uint2*)(xd + xr * XSTR + 8 + xh * 4) = dl;
    }
    if (kk + 1 < iters) {
      const uint4* gB2 = (const uint4*)wt + (size_t)(kt0 + kk + 1) * 1024;
      vb0 = gB2[t]; vb1 = gB2[t + 512];
    }
    __syncthreads();

    // main MFMA on tile kk
    short* ab = a_s[kk & 1];
    short8 aF[4];
#pragma unroll
    for (int i = 0; i < 4; ++i)
      aF[i] = *(const short8*)(ab + (wm * 64 + i * 16 + lm) * ASTR + lq * 8);
#pragma unroll
    for (int j = 0; j < 4; ++j) {
      short8 bF = *(const short8*)(bb + (wn * 64 + j * 16 + lm) * ASTR + lq * 8);
#pragma unroll
      for (int i = 0; i < 4; ++i)
        acc[i][j] = __builtin_amdgcn_mfma_f32_16x16x32_bf16(bF, aF[i], acc[i][j], 0, 0, 0);
    }

    // stage A-subtile for iter kk+1 into the other buffer
    if (kk + 1 < iters) {
      int kn = kk + 1;
      int g2 = kn & 3, grp2 = kn >> 2;
      const short* xs = x_s[grp2 & 1];
      int node2 = n0 + grp2;
      short* ad = a_s[kn & 1];
      int bloc = wave * 16 + lm;
      short8 xf = (short8)0;
      if (lq == 0 || lq == 2) xf = *(const short8*)(xs + bloc * XSTR);
      else if (lq == 1)       xf = *(const short8*)(xs + bloc * XSTR + 8);
#pragma unroll
      for (int tt = 0; tt < 2; ++tt) {
        int ot = g2 * 2 + tt;
        short8 wf = (short8)0;
        if (lq <= 1)      wf = *(const short8*)(rw_s + (ot * 16 + lm) * XSTR);
        else if (lq == 2) wf = *(const short8*)(rw_s + (ot * 16 + lm) * XSTR + 8);
        float4v c = __builtin_amdgcn_mfma_f32_16x16x32_bf16(wf, xf, (float4v)0.f, 0, 0, 0);
        int o0 = ot * 16 + lq * 4;
        float4 cb = *(const float4*)(convb_s + o0);
        unsigned d0 = (unsigned)f2bf(fmaxf(c[0] + cb.x, 0.f)) |
                      ((unsigned)f2bf(fmaxf(c[1] + cb.y, 0.f)) << 16);
        unsigned d1 = (unsigned)f2bf(fmaxf(c[2] + cb.z, 0.f)) |
                      ((unsigned)f2bf(fmaxf(c[3] + cb.w, 0.f)) << 16);
        if (mb == 0 && bloc == 0) {
          const unsigned* f0p = (const unsigned*)(feat0 + ((size_t)node2 * OUTC + o0));
          d0 = f0p[0]; d1 = f0p[1];
        }
        uint2 dd; dd.x = d0; dd.y = d1;
        *(uint2*)(ad + bloc * ASTR + tt * 16 + lq * 4) = dd;
      }
    }
  }

  // epilogue: part layout [b][ch][c]; per-lane dwordx4
  float* pb = part + ((size_t)(mb * 128) * ns + ch) * CTOT;
#pragma unroll
  for (int i = 0; i < 4; ++i) {
    int m = wm * 64 + i * 16 + lm;
#pragma unroll
    for (int j = 0; j < 4; ++j) {
      int c = wn * 64 + j * 16 + lq * 4;
      *(float4v*)(pb + (size_t)m * ns * CTOT + c) = acc[i][j];
    }
  }
}

// ---------------------------------------------------------------------------
// K3 (R19): float4-vectorized split-K reduction (was 64 scalar loads/thread
// = 256 B/wave-instr; now 16 float4 loads = 1 KB/wave-instr) + 4 KB LDS
// combine. Then biases+relu, val MLP, dueling combine (unchanged).
// ---------------------------------------------------------------------------
__global__ __launch_bounds__(256) void final_kernel(
    const float* __restrict__ part, int ns,
    const float* __restrict__ advb, const float* __restrict__ v1b,
    const float* __restrict__ v2w, const float* __restrict__ v2b,
    const float* __restrict__ v3w, const float* __restrict__ v3b,
    float* __restrict__ out)
{
  __shared__ float4v red_s[4][64];   // 4 KB
  __shared__ float adv_s[CADV];
  __shared__ float v1_s[64];
  __shared__ float val2_s[64];
  __shared__ float val3_s[64];
  int b = blockIdx.x, t = threadIdx.x;
  int q = t & 63, r0 = t >> 6;       // col-quad, row-group
  const float4v* p4 = (const float4v*)(part + (size_t)b * ns * CTOT);
  float4v s4 = (float4v)0.f;
  for (int i = r0; i < ns; i += 4) s4 += p4[i * 64 + q];
  red_s[r0][q] = s4;
  __syncthreads();
  float s;
  {
    const float* rs = (const float*)red_s;   // [r][256] floats
    s = rs[t] + rs[256 + t] + rs[512 + t] + rs[768 + t];
  }
  if (t < CADV) adv_s[t] = fmaxf(s + advb[t], 0.f);
  else          v1_s[t - CADV] = fmaxf(s + v1b[t - CADV], 0.f);
  __syncthreads();
  if (t < 64) {
    float a = v2b[t];
#pragma unroll
    for (int i = 0; i < 64; ++i) a += v1_s[i] * v2w[i * 64 + t];
    val2_s[t] = fmaxf(a, 0.f);
  }
  __syncthreads();
  if (t < 64) {
    float a = v3b[t];
#pragma unroll
    for (int j = 0; j < 64; ++j) a += val2_s[j] * v3w[j * 64 + t];
    val3_s[t] = a;
  }
  __syncthreads();
  if (t < CADV) {
    int d = t / 3;
    float mean = (adv_s[d * 3] + adv_s[d * 3 + 1] + adv_s[d * 3 + 2]) * (1.f / 3.f);
    out[(size_t)b * CADV + t] = val3_s[d] + adv_s[t] - mean;
  }
}

extern "C" void kernel_launch(void* const* d_in, const int* in_sizes, int n_in,
                              void* d_out, int out_size, void* d_ws, size_t ws_size,
                              hipStream_t stream)
{
  (void)in_sizes; (void)n_in; (void)out_size;
  const float* x     = (const float*)d_in[0];
  const int*   ei    = (const int*)d_in[1];
  const float* w1    = (const float*)d_in[2];
  const float* b1    = (const float*)d_in[3];
  const float* w2    = (const float*)d_in[4];
  const float* b2    = (const float*)d_in[5];
  const float* rootw = (const float*)d_in[6];
  const float* convb = (const float*)d_in[7];
  const float* advw  = (const float*)d_in[8];
  const float* advb  = (const float*)d_in[9];
  const float* v1w   = (const float*)d_in[10];
  const float* v1b   = (const float*)d_in[11];
  const float* v2w   = (const float*)d_in[12];
  const float* v2b   = (const float*)d_in[13];
  const float* v3w   = (const float*)d_in[14];
  const float* v3b   = (const float*)d_in[15];
  float* out = (float*)d_out;

  const size_t f0B = 131072;                    // feat0 64 KB (padded)
  const size_t wtB = (size_t)Ktot * CTOT * 2;   // 16.8 MB

  int NS = 64;
  while (NS > 8 && f0B + wtB + (size_t)NS * Bsz * CTOT * 4 > ws_size)
    NS >>= 1;

  unsigned short* feat0 = (unsigned short*)d_ws;
  unsigned short* wtp   = (unsigned short*)((char*)d_ws + f0B);
  float* part = (float*)((char*)d_ws + f0B + wtB);

  prep_feat_kernel<<<1040, 256, 0, stream>>>(x, ei, w1, b1, w2, b2, rootw,
                                             convb, advw, v1w, wtp, feat0);
  gemm_mfma<<<dim3(NS, 8), 512, 0, stream>>>(x, wtp, rootw, convb, feat0, part,
                                             1024 / NS, NS);
  final_kernel<<<Bsz, 256, 0, stream>>>(part, NS, advb, v1b, v2w, v2b, v3w, v3b, out);
}